// Round 9
// baseline (128.744 us; speedup 1.0000x reference)
//
#include <hip/hip_runtime.h>
#include <hip/hip_bf16.h>
#include <math.h>

#define M_ROWS 65536
#define NSPLINE 32
#define BM 64            // rows per block (R14-proven)
#define WROWS 16         // rows per wave
#define GROUP 4          // splines per iteration (one per quad q)
#define NITER (NSPLINE / GROUP)   // 8 groups per wave
#define NTILE 9          // ceil(33 params / 4-per-lane) MFMA tiles per group
#define WB_ELEMS (NITER * NTILE * 2 * 64 * 8)   // 73728 fp16 = 144 KiB
#define LOG2E 1.4426950408889634f
#define LN2   0.69314718055994531f

typedef __attribute__((ext_vector_type(8))) _Float16 half8;
typedef __attribute__((ext_vector_type(4))) float floatx4;

// R8/R10-proven poly softplus. Fallback is a ~5-sigma event for this data
// (y-sigma ~0.2): P(any lane diverges) ~6e-4 per site -> branch is free.
// R13 proved the always-2-transcendental version costs +8.5us busy time.
__device__ __forceinline__ float softplus_fast(float t) {
    float u = t * t;
    if (u > 1.21f) return log1pf(__expf(t));   // rare, exact
    float p = fmaf(u, -2.6352e-5f, 3.4722222e-4f);
    p = fmaf(u, p, -5.2083333e-3f);
    p = fmaf(u, p, 0.125f);
    p = fmaf(u, p, 0.69314718f);
    return fmaf(t, 0.5f, p);
}

// ---------------------------------------------------------------------------
// R14-proven pack + R19 delta: WIDTH columns (param 17..32) are pre-scaled
// by log2(e) so the kernel's softmax-exp is a raw v_exp_f32 (exp2) with no
// per-eval multiply. The affine y = W z + b is linear, so scaling W,b width
// columns gives y*log2e exactly; exp(y) == exp2(y*log2e).
// m-mapping per tile tau (R14):
//   m = (spline-sub q_m)*4 + r  ->  column (spline = g*4+q_m, param = tau*4+r)
// A-fragment: lane L, elem j: m = L&15, k = half*32 + (L>>4)*8 + j
//   k<48: W[k][col]; k==48: bias (paired with B=1.0); else 0.
// ---------------------------------------------------------------------------
__global__ void pack_W(const float* __restrict__ W, const float* __restrict__ b,
                       _Float16* __restrict__ WH) {
    int idx = blockIdx.x * 256 + threadIdx.x;     // < 73728
    int j    = idx & 7;
    int lane = (idx >> 3) & 63;
    int half = (idx >> 9) & 1;
    int tile = idx >> 10;        // 0..71 = g*NTILE + tau
    int tau  = tile % NTILE;
    int g    = tile / NTILE;
    int m  = lane & 15;
    int k  = half * 32 + ((lane >> 4) << 3) + j;
    int spline = g * 4 + (m >> 2);
    int param  = tau * 4 + (m & 3);
    float v = 0.0f;
    if (param < 33 && k <= 48) {
        int col = spline * 33 + param;
        v = (k < 48) ? W[k * 1056 + col] : b[col];
        if (param >= 17) v *= LOG2E;              // width columns: exp -> exp2
    }
    WH[idx] = (_Float16)v;
}

// pv[p] lives in the MFMA accumulators; indices are all compile-time.
#define PV(p) (acc[(p) >> 2][(p) & 3])

// ---------------------------------------------------------------------------
// R19 = exact R14 structure (all pipeline variants R11/R12/R18 measured
// neutral-to-worse; the compiler's own schedule of the plain order wins) +
//  (1) WAVE PHASE-STAGGER: wave w does groups in order (g2 + 2w) & 7.
//      All resident waves currently start IN PHASE -> correlated stalls
//      (everyone in the load/MFMA window simultaneously; issue census says
//      VALU needs only ~25-30% of wall, yet VALUBusy reads ~53% and dur is
//      latency-dominated). Staggering gives each CU 4 phase classes so one
//      wave's spline VALU covers another's load window. Groups are
//      independent; only logdet summation order changes (~1e-7).
//  (2) exp2 widths (pack pre-scale) -16 mul/task.
//  (3) 0.5-fold: carry u = h_norm/2 (inv2 = 0.999/S where S = sum (h+h')wd),
//      scan fma uses (u+u')*wd directly; o = ((du*w)*a + 2*lu*w)*a + cdf;
//      logdet accumulated in log2: ln(a*dh+lh) = LN2*(1 + log2(a*du+lu)),
//      final = fmaf(sum_log2, LN2, 32*LN2). -31 mul, -8 mul/task.
// ---------------------------------------------------------------------------
__global__ void __launch_bounds__(256) fused_kernel(
    const float* __restrict__ z, const float* __restrict__ c,
    const _Float16* __restrict__ WH, float* __restrict__ out)
{
    const int tid  = threadIdx.x;
    const int w    = tid >> 6;
    const int lane = tid & 63;
    const int q    = lane >> 4;        // quad 0..3 = spline-sub within group
    const int cc   = lane & 15;        // row within wave
    const int row_base = blockIdx.x * BM + w * WROWS;

    // ---- z2 passthrough: out[:, :32] = z[:, 32:64] for this wave's rows ----
    #pragma unroll
    for (int it = 0; it < 2; ++it) {
        int idx = it * 64 + lane;                 // 0..127 = 16 rows x 8 float4
        int rr  = row_base + (idx >> 3);
        int v4  = idx & 7;
        float4 val = *(const float4*)(z + (size_t)rr * 64 + 32 + v4 * 4);
        *(float4*)(out + (size_t)rr * 64 + v4 * 4) = val;
    }

    // ---- z2c fragments (fp16, persist): the B operand ---------------------
    // B[k=(q*8+j)][n=cc] = z2c[row cc][k]
    half8 a0, a1;
    {
        const float* zr = z + (size_t)(row_base + cc) * 64 + 32;
        float4 v0 = *(const float4*)(zr + q * 8);
        float4 v1 = *(const float4*)(zr + q * 8 + 4);
        a0[0]=(_Float16)v0.x; a0[1]=(_Float16)v0.y;
        a0[2]=(_Float16)v0.z; a0[3]=(_Float16)v0.w;
        a0[4]=(_Float16)v1.x; a0[5]=(_Float16)v1.y;
        a0[6]=(_Float16)v1.z; a0[7]=(_Float16)v1.w;
        if (q < 2) {
            const float* cr = c + (size_t)(row_base + cc) * 16 + q * 8;
            float4 u0 = *(const float4*)cr;
            float4 u1 = *(const float4*)(cr + 4);
            a1[0]=(_Float16)u0.x; a1[1]=(_Float16)u0.y;
            a1[2]=(_Float16)u0.z; a1[3]=(_Float16)u0.w;
            a1[4]=(_Float16)u1.x; a1[5]=(_Float16)u1.y;
            a1[6]=(_Float16)u1.z; a1[7]=(_Float16)u1.w;
        } else {
            #pragma unroll
            for (int j = 0; j < 8; ++j) a1[j] = (_Float16)0.0f;
            if (q == 2) a1[0] = (_Float16)1.0f;   // k=48 bias row
        }
    }

    // z1 base for this lane's spline inputs: z[row cc][n = g*4 + q]
    const float* z1p = z + (size_t)(row_base + cc) * 64 + q;

    float ld_acc = 0.0f;   // accumulates log2 terms (R19: scaled once at end)

    #pragma unroll 1
    for (int g2 = 0; g2 < NITER; ++g2) {
        const int g = (g2 + 2 * w) & 7;     // phase-stagger across waves
        const float in = z1p[g * 4];        // hot L1 line

        // ---- GEMM: 9 tiles x (K=32 + K=16+bias) -> pv in registers --------
        floatx4 acc[NTILE];
        const half8* base = (const half8*)WH + (size_t)g * (NTILE * 2 * 64) + lane;
        #pragma unroll
        for (int t = 0; t < NTILE; ++t) {
            half8 w0 = base[(t * 2 + 0) * 64];
            half8 w1 = base[(t * 2 + 1) * 64];
            floatx4 a = {0.f, 0.f, 0.f, 0.f};
            a = __builtin_amdgcn_mfma_f32_16x16x32_f16(w0, a0, a, 0, 0, 0);
            a = __builtin_amdgcn_mfma_f32_16x16x32_f16(w1, a1, a, 0, 0, 0);
            acc[t] = a;
        }
        // lane (q,cc) now holds PV(p) = y[row cc][spline g*4+q][param p]
        // (width params 17..32 pre-scaled by log2e).

        // ---- spline on registers -----------------------------------------
        const int n = g * GROUP + q;

        float wd[16];
        float sew = 0.f;
        #pragma unroll
        for (int i = 0; i < 16; ++i) {
            float e = __builtin_amdgcn_exp2f(PV(17 + i));   // raw v_exp_f32
            wd[i] = e; sew += e;
        }
        const float inv_sew = 0.984f * __builtin_amdgcn_rcpf(sew);
        #pragma unroll
        for (int i = 0; i < 16; ++i) wd[i] = 0.001f + wd[i] * inv_sew;

        float hp[17];                       // pre-normalization heights
        #pragma unroll
        for (int i = 0; i < 17; ++i)
            hp[i] = softplus_fast(PV(i)) + 0.001f;

        // S = sum (hp[i]+hp[i+1])*wd[i] = 2*area ; u = h_norm/2:
        // u = 0.5*(0.001 + hp*(0.999/area)) = 0.0005 + hp*(0.999/S)
        float S = 0.f;
        #pragma unroll
        for (int i = 0; i < 16; ++i) S = fmaf(hp[i] + hp[i + 1], wd[i], S);
        const float inv2 = 0.999f * __builtin_amdgcn_rcpf(S);
        float u[17];
        #pragma unroll
        for (int i = 0; i < 17; ++i) u[i] = fmaf(hp[i], inv2, 0.0005f);

        // scan: cdf accumulates (u+u')*wd == (h+h')*0.5*wd  (normalized)
        float loc = 0.f, cdfl = 0.f;
        float sel_loc = 0.f, sel_w = wd[0], sel_cdf = 0.f;
        float sel_lu = u[0], sel_ru = u[1];
        #pragma unroll
        for (int bn = 1; bn < 16; ++bn) {
            cdfl = fmaf(u[bn - 1] + u[bn], wd[bn - 1], cdfl);
            loc += wd[bn - 1];
            if (in >= loc) {                        // monotone: last true wins
                sel_loc = loc; sel_w = wd[bn]; sel_cdf = cdfl;
                sel_lu = u[bn]; sel_ru = u[bn + 1];
            }
        }

        const float alpha = (in - sel_loc) * __builtin_amdgcn_rcpf(sel_w);
        const float du    = sel_ru - sel_lu;        // = dh/2
        const float lw    = sel_lu * sel_w;         // = lh*w/2
        // o = (0.5*dh*w)*a^2 + (lh*w)*a + cdf = ((du*w)*a + 2*lw)*a + cdf
        float o = fmaf(fmaf(du * sel_w, alpha, lw + lw), alpha, sel_cdf);
        o = fminf(fmaxf(o, 0.0f), 1.0f);
        out[(size_t)(row_base + cc) * 64 + 32 + n] = o;
        // ln(a*dh + lh) = LN2 * (1 + log2(a*du + lu)); defer scale+offset
        ld_acc += __builtin_amdgcn_logf(fmaf(alpha, du, sel_lu));
    }

    // ---- logdet: lanes {cc, cc+16, cc+32, cc+48} hold row cc's partials ---
    ld_acc += __shfl_down(ld_acc, 32, 64);
    ld_acc += __shfl_down(ld_acc, 16, 64);
    if (q == 0)   // 32 log2-terms: ln2*(sum + 32)
        out[(size_t)M_ROWS * 64 + row_base + cc] =
            fmaf(ld_acc, LN2, 32.0f * LN2);
}

extern "C" void kernel_launch(void* const* d_in, const int* in_sizes, int n_in,
                              void* d_out, int out_size, void* d_ws, size_t ws_size,
                              hipStream_t stream) {
    const float* c = (const float*)d_in[0];   // (M, 16)
    const float* z = (const float*)d_in[1];   // (M, 64)
    const float* W = (const float*)d_in[2];   // (48, 1056)
    const float* b = (const float*)d_in[3];   // (1056,)
    float* out = (float*)d_out;               // M*64 (x) then M (logdet)
    _Float16* WH = (_Float16*)d_ws;           // 73728 fp16 = 144 KiB

    pack_W<<<WB_ELEMS / 256, 256, 0, stream>>>(W, b, WH);
    fused_kernel<<<M_ROWS / BM, 256, 0, stream>>>(z, c, WH, out);
}

// Round 10
// 106.425 us; speedup vs baseline: 1.2097x; 1.2097x over previous
//
#include <hip/hip_runtime.h>
#include <hip/hip_bf16.h>
#include <math.h>

#define M_ROWS 65536
#define NSPLINE 32
#define BM 64            // rows per block (R14-proven)
#define WROWS 16         // rows per wave
#define GROUP 4          // splines per iteration (one per quad q)
#define NITER (NSPLINE / GROUP)   // 8 groups per wave
#define NTILE 9          // ceil(33 params / 4-per-lane) MFMA tiles per group
#define WB_ELEMS (NITER * NTILE * 2 * 64 * 8)   // 73728 fp16 = 144 KiB
#define LOG2E 1.4426950408889634f
#define LN2   0.69314718055994531f

typedef __attribute__((ext_vector_type(8))) _Float16 half8;
typedef __attribute__((ext_vector_type(4))) float floatx4;

// R8/R10-proven poly softplus. Fallback is a ~5-sigma event for this data
// (y-sigma ~0.2): P(any lane diverges) ~6e-4 per site -> branch is free.
// R13 proved the always-2-transcendental version costs +8.5us busy time.
__device__ __forceinline__ float softplus_fast(float t) {
    float u = t * t;
    if (u > 1.21f) return log1pf(__expf(t));   // rare, exact
    float p = fmaf(u, -2.6352e-5f, 3.4722222e-4f);
    p = fmaf(u, p, -5.2083333e-3f);
    p = fmaf(u, p, 0.125f);
    p = fmaf(u, p, 0.69314718f);
    return fmaf(t, 0.5f, p);
}

// ---------------------------------------------------------------------------
// R14-proven pack + exp2 pre-scale: WIDTH columns (param 17..32) scaled by
// log2(e) at pack time, so softmax-exp in the kernel is a raw v_exp_f32
// (exp2) with no per-eval multiply. Affine y = Wz+b is linear, so scaling
// the W,b width columns yields y*log2e exactly; exp(y) == exp2(y*log2e).
// m-mapping per tile tau (R14):
//   m = (spline-sub q_m)*4 + r  ->  column (spline = g*4+q_m, param = tau*4+r)
// A-fragment: lane L, elem j: m = L&15, k = half*32 + (L>>4)*8 + j
//   k<48: W[k][col]; k==48: bias (paired with B=1.0); else 0.
// ---------------------------------------------------------------------------
__global__ void pack_W(const float* __restrict__ W, const float* __restrict__ b,
                       _Float16* __restrict__ WH) {
    int idx = blockIdx.x * 256 + threadIdx.x;     // < 73728
    int j    = idx & 7;
    int lane = (idx >> 3) & 63;
    int half = (idx >> 9) & 1;
    int tile = idx >> 10;        // 0..71 = g*NTILE + tau
    int tau  = tile % NTILE;
    int g    = tile / NTILE;
    int m  = lane & 15;
    int k  = half * 32 + ((lane >> 4) << 3) + j;
    int spline = g * 4 + (m >> 2);
    int param  = tau * 4 + (m & 3);
    float v = 0.0f;
    if (param < 33 && k <= 48) {
        int col = spline * 33 + param;
        v = (k < 48) ? W[k * 1056 + col] : b[col];
        if (param >= 17) v *= LOG2E;              // width columns: exp -> exp2
    }
    WH[idx] = (_Float16)v;
}

// pv[p] lives in the MFMA accumulators; indices are all compile-time.
#define PV(p) (acc[(p) >> 2][(p) & 3])

// ---------------------------------------------------------------------------
// R20 = EXACT R14 structure + arithmetic slimming only (single variable vs
// R14). R19's regression is attributed to the wave phase-stagger: in-phase
// waves share one 18KB WH slice in L1 (constructive sharing); staggered,
// 4 slices = 72KB > 32KB L1 -> thrash (VALUBusy fell 53->38). Every
// scheduling intervention to date (pipeline x3, grid-split x2, stagger x1)
// lost to the plain R14 order; this keeps it byte-for-byte and only deletes
// VALU work (~55 ops/task):
//  - exp2 widths via pack pre-scale (-16 mul)
//  - 0.5-fold: u = h_norm/2, inv2 = 0.999/S with S = sum (hp+hp')*wd;
//    scan fma uses (u+u')*wd; o = ((du*w)*a + 2*(lu*w))*a + cdf  (-31 ops)
//  - logdet in log2: ln(a*dh+lh) = LN2*(1 + log2(a*du+lu)); one final
//    fmaf(sum, LN2, 32*LN2) per row  (-8 ops)
// absmax must stay 0.015625 (fp16-GEMM-dominated; verified identical in R19).
// ---------------------------------------------------------------------------
__global__ void __launch_bounds__(256) fused_kernel(
    const float* __restrict__ z, const float* __restrict__ c,
    const _Float16* __restrict__ WH, float* __restrict__ out)
{
    const int tid  = threadIdx.x;
    const int w    = tid >> 6;
    const int lane = tid & 63;
    const int q    = lane >> 4;        // quad 0..3 = spline-sub within group
    const int cc   = lane & 15;        // row within wave
    const int row_base = blockIdx.x * BM + w * WROWS;

    // ---- z2 passthrough: out[:, :32] = z[:, 32:64] for this wave's rows ----
    #pragma unroll
    for (int it = 0; it < 2; ++it) {
        int idx = it * 64 + lane;                 // 0..127 = 16 rows x 8 float4
        int rr  = row_base + (idx >> 3);
        int v4  = idx & 7;
        float4 val = *(const float4*)(z + (size_t)rr * 64 + 32 + v4 * 4);
        *(float4*)(out + (size_t)rr * 64 + v4 * 4) = val;
    }

    // ---- z2c fragments (fp16, persist): the B operand ---------------------
    // B[k=(q*8+j)][n=cc] = z2c[row cc][k]
    half8 a0, a1;
    {
        const float* zr = z + (size_t)(row_base + cc) * 64 + 32;
        float4 v0 = *(const float4*)(zr + q * 8);
        float4 v1 = *(const float4*)(zr + q * 8 + 4);
        a0[0]=(_Float16)v0.x; a0[1]=(_Float16)v0.y;
        a0[2]=(_Float16)v0.z; a0[3]=(_Float16)v0.w;
        a0[4]=(_Float16)v1.x; a0[5]=(_Float16)v1.y;
        a0[6]=(_Float16)v1.z; a0[7]=(_Float16)v1.w;
        if (q < 2) {
            const float* cr = c + (size_t)(row_base + cc) * 16 + q * 8;
            float4 u0 = *(const float4*)cr;
            float4 u1 = *(const float4*)(cr + 4);
            a1[0]=(_Float16)u0.x; a1[1]=(_Float16)u0.y;
            a1[2]=(_Float16)u0.z; a1[3]=(_Float16)u0.w;
            a1[4]=(_Float16)u1.x; a1[5]=(_Float16)u1.y;
            a1[6]=(_Float16)u1.z; a1[7]=(_Float16)u1.w;
        } else {
            #pragma unroll
            for (int j = 0; j < 8; ++j) a1[j] = (_Float16)0.0f;
            if (q == 2) a1[0] = (_Float16)1.0f;   // k=48 bias row
        }
    }

    // z1 base for this lane's spline inputs: z[row cc][n = g*4 + q]
    const float* z1p = z + (size_t)(row_base + cc) * 64 + q;

    float ld_acc = 0.0f;   // accumulates log2 terms; scaled once at the end

    #pragma unroll 1
    for (int g = 0; g < NITER; ++g) {
        const float in = z1p[g * 4];        // hot L1 line

        // ---- GEMM: 9 tiles x (K=32 + K=16+bias) -> pv in registers --------
        floatx4 acc[NTILE];
        const half8* base = (const half8*)WH + (size_t)g * (NTILE * 2 * 64) + lane;
        #pragma unroll
        for (int t = 0; t < NTILE; ++t) {
            half8 w0 = base[(t * 2 + 0) * 64];
            half8 w1 = base[(t * 2 + 1) * 64];
            floatx4 a = {0.f, 0.f, 0.f, 0.f};
            a = __builtin_amdgcn_mfma_f32_16x16x32_f16(w0, a0, a, 0, 0, 0);
            a = __builtin_amdgcn_mfma_f32_16x16x32_f16(w1, a1, a, 0, 0, 0);
            acc[t] = a;
        }
        // lane (q,cc) now holds PV(p) = y[row cc][spline g*4+q][param p]
        // (width params 17..32 pre-scaled by log2e).

        // ---- spline on registers -----------------------------------------
        const int n = g * GROUP + q;

        float wd[16];
        float sew = 0.f;
        #pragma unroll
        for (int i = 0; i < 16; ++i) {
            float e = __builtin_amdgcn_exp2f(PV(17 + i));   // raw v_exp_f32
            wd[i] = e; sew += e;
        }
        const float inv_sew = 0.984f * __builtin_amdgcn_rcpf(sew);
        #pragma unroll
        for (int i = 0; i < 16; ++i) wd[i] = 0.001f + wd[i] * inv_sew;

        float hp[17];                       // pre-normalization heights
        #pragma unroll
        for (int i = 0; i < 17; ++i)
            hp[i] = softplus_fast(PV(i)) + 0.001f;

        // S = sum (hp[i]+hp[i+1])*wd[i] = 2*area_pre; u = h_norm/2:
        // u = 0.5*(0.001 + hp*0.999/area) = 0.0005 + hp*(0.999/S)
        float S = 0.f;
        #pragma unroll
        for (int i = 0; i < 16; ++i) S = fmaf(hp[i] + hp[i + 1], wd[i], S);
        const float inv2 = 0.999f * __builtin_amdgcn_rcpf(S);
        float u[17];
        #pragma unroll
        for (int i = 0; i < 17; ++i) u[i] = fmaf(hp[i], inv2, 0.0005f);

        // scan: cdf accumulates (u+u')*wd == (h+h')*0.5*wd (normalized)
        float loc = 0.f, cdfl = 0.f;
        float sel_loc = 0.f, sel_w = wd[0], sel_cdf = 0.f;
        float sel_lu = u[0], sel_ru = u[1];
        #pragma unroll
        for (int bn = 1; bn < 16; ++bn) {
            cdfl = fmaf(u[bn - 1] + u[bn], wd[bn - 1], cdfl);
            loc += wd[bn - 1];
            if (in >= loc) {                        // monotone: last true wins
                sel_loc = loc; sel_w = wd[bn]; sel_cdf = cdfl;
                sel_lu = u[bn]; sel_ru = u[bn + 1];
            }
        }

        const float alpha = (in - sel_loc) * __builtin_amdgcn_rcpf(sel_w);
        const float du    = sel_ru - sel_lu;        // = dh/2
        const float lw    = sel_lu * sel_w;         // = lh*w/2
        // o = (0.5*dh*w)*a^2 + (lh*w)*a + cdf = ((du*w)*a + 2*lw)*a + cdf
        float o = fmaf(fmaf(du * sel_w, alpha, lw + lw), alpha, sel_cdf);
        o = fminf(fmaxf(o, 0.0f), 1.0f);
        out[(size_t)(row_base + cc) * 64 + 32 + n] = o;
        // ln(a*dh + lh) = LN2*(1 + log2(a*du + lu)); defer scale+offset
        ld_acc += __builtin_amdgcn_logf(fmaf(alpha, du, sel_lu));
    }

    // ---- logdet: lanes {cc, cc+16, cc+32, cc+48} hold row cc's partials ---
    ld_acc += __shfl_down(ld_acc, 32, 64);
    ld_acc += __shfl_down(ld_acc, 16, 64);
    if (q == 0)   // 32 log2-terms: ln2*(sum + 32)
        out[(size_t)M_ROWS * 64 + row_base + cc] =
            fmaf(ld_acc, LN2, 32.0f * LN2);
}

extern "C" void kernel_launch(void* const* d_in, const int* in_sizes, int n_in,
                              void* d_out, int out_size, void* d_ws, size_t ws_size,
                              hipStream_t stream) {
    const float* c = (const float*)d_in[0];   // (M, 16)
    const float* z = (const float*)d_in[1];   // (M, 64)
    const float* W = (const float*)d_in[2];   // (48, 1056)
    const float* b = (const float*)d_in[3];   // (1056,)
    float* out = (float*)d_out;               // M*64 (x) then M (logdet)
    _Float16* WH = (_Float16*)d_ws;           // 73728 fp16 = 144 KiB

    pack_W<<<WB_ELEMS / 256, 256, 0, stream>>>(W, b, WH);
    fused_kernel<<<M_ROWS / BM, 256, 0, stream>>>(z, c, WH, out);
}